// Round 1
// baseline (304.512 us; speedup 1.0000x reference)
//
#include <hip/hip_runtime.h>

typedef __attribute__((ext_vector_type(4))) float f32x4;
typedef __attribute__((ext_vector_type(8))) short bf16x8;
typedef __attribute__((ext_vector_type(4))) unsigned int u32x4;

#define EPSV 1e-5f

// workspace layout (bytes)
#define OFF_BUFA 0u
#define OFF_BUFB 33554432u
#define OFF_T    67108864u
#define OFF_WQ1  (OFF_T + 0u)       // f32 [128][12]  (9 taps used)
#define OFF_R3F  (OFF_T + 6144u)    // f32 [9][128]   integer-valued
#define OFF_CST3 (OFF_T + 10752u)   // f32x4 [128]
#define OFF_CST1 (OFF_T + 12800u)   // f32x4 [128]
#define OFF_R2BF (OFF_T + 14848u)   // bf16 [128][128]
#define OFF_CST2 (OFF_T + 47616u)   // f32x4 [128]
#define OFF_R4BF (OFF_T + 49664u)   // bf16 [128][128]
#define OFF_CST4 (OFF_T + 82432u)   // f32x4 [128]
#define OFF_R5BF (OFF_T + 84480u)   // bf16 [32][128] (rows 19..31 zero)
#define OFF_CST5 (OFF_T + 92672u)   // float2 [32]

struct PArgs {
  const float *dw1, *pw1, *dw2, *pw2, *clsw, *clsb;
  const float *g1, *b1, *m1, *v1;
  const float *g2, *b2, *m2, *v2;
  const float *g3, *b3, *m3, *v3;
  const float *g4, *b4, *m4, *v4;
  const float *s1, *s2, *s3, *s4;
};

__device__ __forceinline__ unsigned short f2bf(float f) {
  // exact for small integers (low mantissa bits are zero)
  return (unsigned short)(__builtin_bit_cast(unsigned int, f) >> 16);
}
__device__ __forceinline__ float clip7(float r) { return fminf(fmaxf(r, -7.f), 7.f); }

// y = a*A; t = (y-m)*sc + b; k = clamp(rint(t/s),0,15).  c = {A, sc, m, b}
__device__ __forceinline__ unsigned int qstep(float a, f32x4 c, float s) {
  float t = (a * c.x - c.z) * c.y + c.w;
  float u = t / s;
  float k = fminf(fmaxf(rintf(u), 0.f), 15.f);
  return (unsigned int)k;
}

// 4 u8 -> 2 dwords of packed bf16 (k ascending: low short = lower k)
__device__ __forceinline__ void cvt2(unsigned int d, unsigned int &lo, unsigned int &hi) {
  float f0 = (float)(d & 0xffu);
  float f1 = (float)((d >> 8) & 0xffu);
  float f2 = (float)((d >> 16) & 0xffu);
  float f3 = (float)(d >> 24);
  lo = (__builtin_bit_cast(unsigned int, f0) >> 16) | (__builtin_bit_cast(unsigned int, f1) & 0xffff0000u);
  hi = (__builtin_bit_cast(unsigned int, f2) >> 16) | (__builtin_bit_cast(unsigned int, f3) & 0xffff0000u);
}

__device__ __forceinline__ float wmax16(float v) {
  #pragma unroll
  for (int s = 1; s < 16; s <<= 1) v = fmaxf(v, __shfl_xor(v, s));
  return v;
}
__device__ __forceinline__ float wmax64(float v) {
  #pragma unroll
  for (int s = 1; s < 64; s <<= 1) v = fmaxf(v, __shfl_xor(v, s));
  return v;
}

// ---------------- prep: quantize weights, fold BN constants ----------------
__global__ __launch_bounds__(64) void prep_kernel(PArgs P, char* __restrict__ ws) {
  int bi = blockIdx.x, l = threadIdx.x;
  float* wq1 = (float*)(ws + OFF_WQ1);
  float* r3f = (float*)(ws + OFF_R3F);
  f32x4* cst1 = (f32x4*)(ws + OFF_CST1);
  f32x4* cst2 = (f32x4*)(ws + OFF_CST2);
  f32x4* cst3 = (f32x4*)(ws + OFF_CST3);
  f32x4* cst4 = (f32x4*)(ws + OFF_CST4);
  unsigned short* r2 = (unsigned short*)(ws + OFF_R2BF);
  unsigned short* r4 = (unsigned short*)(ws + OFF_R4BF);
  unsigned short* r5 = (unsigned short*)(ws + OFF_R5BF);
  float2* cst5 = (float2*)(ws + OFF_CST5);

  if (bi < 128) {                       // dw1: fp32 quantized weights
    int c = bi;
    float w = (l < 9) ? P.dw1[c * 9 + l] : 0.f;
    float mx = wmax16(fabsf(w));
    float sq = fmaxf(mx / 7.0f, 1e-8f);
    if (l < 9) wq1[c * 12 + l] = clip7(rintf(w / sq)) * sq;
    if (l == 0) {
      float sc = P.g1[c] / sqrtf(P.v1[c] + EPSV);
      cst1[c] = f32x4{1.f, sc, P.m1[c], P.b1[c]};
    }
  } else if (bi < 256) {                // pw1: int weights as bf16
    int o = bi - 128;
    float w0 = P.pw1[o * 128 + l], w1 = P.pw1[o * 128 + 64 + l];
    float mx = wmax64(fmaxf(fabsf(w0), fabsf(w1)));
    float sq = fmaxf(mx / 7.0f, 1e-8f);
    r2[o * 128 + l]      = f2bf(clip7(rintf(w0 / sq)));
    r2[o * 128 + 64 + l] = f2bf(clip7(rintf(w1 / sq)));
    if (l == 0) {
      float sc = P.g2[o] / sqrtf(P.v2[o] + EPSV);
      cst2[o] = f32x4{P.s1[0] * sq, sc, P.m2[o], P.b2[o]};
    }
  } else if (bi < 384) {                // dw2: int weights as f32
    int c = bi - 256;
    float w = (l < 9) ? P.dw2[c * 9 + l] : 0.f;
    float mx = wmax16(fabsf(w));
    float sq = fmaxf(mx / 7.0f, 1e-8f);
    if (l < 9) r3f[l * 128 + c] = clip7(rintf(w / sq));
    if (l == 0) {
      float sc = P.g3[c] / sqrtf(P.v3[c] + EPSV);
      cst3[c] = f32x4{P.s2[0] * sq, sc, P.m3[c], P.b3[c]};
    }
  } else if (bi < 512) {                // pw2
    int o = bi - 384;
    float w0 = P.pw2[o * 128 + l], w1 = P.pw2[o * 128 + 64 + l];
    float mx = wmax64(fmaxf(fabsf(w0), fabsf(w1)));
    float sq = fmaxf(mx / 7.0f, 1e-8f);
    r4[o * 128 + l]      = f2bf(clip7(rintf(w0 / sq)));
    r4[o * 128 + 64 + l] = f2bf(clip7(rintf(w1 / sq)));
    if (l == 0) {
      float sc = P.g4[o] / sqrtf(P.v4[o] + EPSV);
      cst4[o] = f32x4{P.s3[0] * sq, sc, P.m4[o], P.b4[o]};
    }
  } else {                              // classifier (rows 19..31 zero-padded)
    int o = bi - 512;
    if (o < 19) {
      float w0 = P.clsw[o * 128 + l], w1 = P.clsw[o * 128 + 64 + l];
      float mx = wmax64(fmaxf(fabsf(w0), fabsf(w1)));
      float sq = fmaxf(mx / 7.0f, 1e-8f);
      r5[o * 128 + l]      = f2bf(clip7(rintf(w0 / sq)));
      r5[o * 128 + 64 + l] = f2bf(clip7(rintf(w1 / sq)));
      if (l == 0) {
        float A5 = P.s4[0] * sq;
        float bq = rintf(P.clsb[o] / A5) * A5;
        cst5[o] = make_float2(A5, bq);
      }
    } else {
      r5[o * 128 + l] = 0; r5[o * 128 + 64 + l] = 0;
      if (l == 0) cst5[o] = make_float2(0.f, 0.f);
    }
  }
}

// ---------------- dw-conv1 (fp32) + BN1 + qrelu; NCHW f32 -> NHWC u8 ----------------
__global__ __launch_bounds__(256) void dw1_kernel(const float* __restrict__ x,
                                                  char* __restrict__ ws,
                                                  const float* __restrict__ s1p) {
  __shared__ unsigned char tile[64 * 132];   // [w][c], stride 132 kills bank conflicts
  int bid = blockIdx.x;
  int wb = bid & 3, h = (bid >> 2) & 127, b = bid >> 9;
  int w0 = wb << 6;
  int wt = threadIdx.x & 63, cg = threadIdx.x >> 6;
  const float* wq1 = (const float*)(ws + OFF_WQ1);
  const f32x4* cst1 = (const f32x4*)(ws + OFF_CST1);
  float s_act = *s1p;
  int gw = w0 + wt;

  for (int cc = 0; cc < 32; cc++) {
    int c = (cg << 5) + cc;
    const float* wp = wq1 + c * 12;
    float k0 = wp[0], k1 = wp[1], k2 = wp[2], k3 = wp[3], k4 = wp[4],
          k5 = wp[5], k6 = wp[6], k7 = wp[7], k8 = wp[8];
    const float* xp = x + (((size_t)((b << 7) + c)) << 15) + (h << 8);
    float y = 0.f;
    if (h > 0) {
      const float* r = xp - 256;
      float a0 = (gw > 0) ? r[gw - 1] : 0.f;
      float a1 = r[gw];
      float a2 = (gw < 255) ? r[gw + 1] : 0.f;
      y = fmaf(a0, k0, y); y = fmaf(a1, k1, y); y = fmaf(a2, k2, y);
    }
    {
      const float* r = xp;
      float a0 = (gw > 0) ? r[gw - 1] : 0.f;
      float a1 = r[gw];
      float a2 = (gw < 255) ? r[gw + 1] : 0.f;
      y = fmaf(a0, k3, y); y = fmaf(a1, k4, y); y = fmaf(a2, k5, y);
    }
    if (h < 127) {
      const float* r = xp + 256;
      float a0 = (gw > 0) ? r[gw - 1] : 0.f;
      float a1 = r[gw];
      float a2 = (gw < 255) ? r[gw + 1] : 0.f;
      y = fmaf(a0, k6, y); y = fmaf(a1, k7, y); y = fmaf(a2, k8, y);
    }
    tile[wt * 132 + c] = (unsigned char)qstep(y, cst1[c], s_act);
  }
  __syncthreads();
  // cooperative de-padded NHWC store: 64 rows x 128 B
  int r = threadIdx.x >> 2, c4 = threadIdx.x & 3;
  unsigned int d0[4], d1[4];
  #pragma unroll
  for (int j = 0; j < 4; j++) d0[j] = *(const unsigned int*)&tile[r * 132 + c4 * 32 + 4 * j];
  #pragma unroll
  for (int j = 0; j < 4; j++) d1[j] = *(const unsigned int*)&tile[r * 132 + c4 * 32 + 16 + 4 * j];
  unsigned char* op = (unsigned char*)(ws + OFF_BUFA) +
                      (((size_t)(((b << 7) + h) << 8) + w0) << 7);
  *(u32x4*)(op + r * 128 + c4 * 32)      = u32x4{d0[0], d0[1], d0[2], d0[3]};
  *(u32x4*)(op + r * 128 + c4 * 32 + 16) = u32x4{d1[0], d1[1], d1[2], d1[3]};
}

// ---------------- pointwise conv (bf16 MFMA, exact int) + BN + qrelu ----------------
// in: NHWC u8 [262144][128], out: same. rbf: bf16 [128][128]. 32 positions/block.
__global__ __launch_bounds__(256) void pw_kernel(const unsigned char* __restrict__ in,
                                                 unsigned char* __restrict__ out,
                                                 const unsigned short* __restrict__ rbf,
                                                 const f32x4* __restrict__ cst,
                                                 const float* __restrict__ sp) {
  __shared__ unsigned char lds[8192];       // B fragments, pre-arranged per-lane order
  int tid = threadIdx.x;
  int p0 = blockIdx.x << 5;
  {
    int p = tid >> 3, q = tid & 7;
    int kc = q >> 1, lg = (q & 1) << 1, pt = p >> 4;
    u32x4 g = *(const u32x4*)(in + (size_t)(p0 + p) * 128 + q * 16);
    unsigned int a0, a1, a2, a3, a4, a5, a6, a7;
    cvt2(g.x, a0, a1); cvt2(g.y, a2, a3); cvt2(g.z, a4, a5); cvt2(g.w, a6, a7);
    int l1 = (p & 15) | (lg << 4);
    int ad = (((((pt << 2) + kc) << 6) | l1) << 4);
    *(u32x4*)(lds + ad)       = u32x4{a0, a1, a2, a3};
    *(u32x4*)(lds + ad + 256) = u32x4{a4, a5, a6, a7};
  }
  __syncthreads();
  int l = tid & 63, wv = tid >> 6;
  int ob = wv << 5;                          // wave owns 32 output channels
  bf16x8 af[2][4];
  #pragma unroll
  for (int ot = 0; ot < 2; ot++)
    #pragma unroll
    for (int kc = 0; kc < 4; kc++) {
      int o = ob + (ot << 4) + (l & 15);
      int k = (kc << 5) + ((l >> 4) << 3);
      af[ot][kc] = *(const bf16x8*)(rbf + o * 128 + k);
    }
  f32x4 acc[2][2] = {{{0,0,0,0},{0,0,0,0}},{{0,0,0,0},{0,0,0,0}}};
  #pragma unroll
  for (int kc = 0; kc < 4; kc++) {
    bf16x8 b0 = *(const bf16x8*)(lds + (((kc << 6) + l) << 4));
    bf16x8 b1 = *(const bf16x8*)(lds + ((((4 + kc) << 6) + l) << 4));
    #pragma unroll
    for (int ot = 0; ot < 2; ot++) {
      acc[ot][0] = __builtin_amdgcn_mfma_f32_16x16x32_bf16(af[ot][kc], b0, acc[ot][0], 0, 0, 0);
      acc[ot][1] = __builtin_amdgcn_mfma_f32_16x16x32_bf16(af[ot][kc], b1, acc[ot][1], 0, 0, 0);
    }
  }
  float s_act = *sp;
  #pragma unroll
  for (int ot = 0; ot < 2; ot++) {
    int o0 = ob + (ot << 4) + ((l >> 4) << 2);
    f32x4 c0 = cst[o0], c1 = cst[o0 + 1], c2 = cst[o0 + 2], c3 = cst[o0 + 3];
    #pragma unroll
    for (int pt = 0; pt < 2; pt++) {
      int p = p0 + (pt << 4) + (l & 15);
      f32x4 a = acc[ot][pt];
      unsigned int pk = qstep(a.x, c0, s_act) | (qstep(a.y, c1, s_act) << 8) |
                        (qstep(a.z, c2, s_act) << 16) | (qstep(a.w, c3, s_act) << 24);
      *(unsigned int*)(out + (size_t)p * 128 + o0) = pk;
    }
  }
}

// ---------------- dw-conv2 (exact int in fp32) + BN3 + qrelu; NHWC u8 -> u8 ----------------
__global__ __launch_bounds__(256) void dw2_kernel(const unsigned char* __restrict__ in,
                                                  unsigned char* __restrict__ out,
                                                  const char* __restrict__ ws,
                                                  const float* __restrict__ sp) {
  __shared__ float tabs[1664];              // r3f [9][128] then cst3 [128]x4
  const float* src = (const float*)(ws + OFF_R3F);
  for (int i = threadIdx.x; i < 1664; i += 256) tabs[i] = src[i];
  __syncthreads();
  int tid = threadIdx.x;
  int cq = tid & 31, pl = tid >> 5;
  int c4 = cq << 2;
  float wk[9][4];
  #pragma unroll
  for (int t = 0; t < 9; t++) {
    wk[t][0] = tabs[t * 128 + c4];     wk[t][1] = tabs[t * 128 + c4 + 1];
    wk[t][2] = tabs[t * 128 + c4 + 2]; wk[t][3] = tabs[t * 128 + c4 + 3];
  }
  const f32x4* cst3 = (const f32x4*)(tabs + 1152);
  f32x4 cs0 = cst3[c4], cs1 = cst3[c4 + 1], cs2 = cst3[c4 + 2], cs3 = cst3[c4 + 3];
  float s_act = *sp;
  int p0 = blockIdx.x << 5;
  #pragma unroll
  for (int j = 0; j < 4; j++) {
    int p = p0 + pl + (j << 3);
    int w = p & 255, hh = (p >> 8) & 127;
    float a0 = 0.f, a1 = 0.f, a2 = 0.f, a3 = 0.f;
    #pragma unroll
    for (int dh = -1; dh <= 1; dh++) {
      if (hh + dh < 0 || hh + dh > 127) continue;
      #pragma unroll
      for (int dw = -1; dw <= 1; dw++) {
        if (w + dw < 0 || w + dw > 255) continue;
        unsigned int v = *(const unsigned int*)(in + (size_t)(p + dh * 256 + dw) * 128 + c4);
        int t = (dh + 1) * 3 + (dw + 1);
        a0 = fmaf((float)(v & 0xffu),         wk[t][0], a0);
        a1 = fmaf((float)((v >> 8) & 0xffu),  wk[t][1], a1);
        a2 = fmaf((float)((v >> 16) & 0xffu), wk[t][2], a2);
        a3 = fmaf((float)(v >> 24),           wk[t][3], a3);
      }
    }
    unsigned int pk = qstep(a0, cs0, s_act) | (qstep(a1, cs1, s_act) << 8) |
                      (qstep(a2, cs2, s_act) << 16) | (qstep(a3, cs3, s_act) << 24);
    *(unsigned int*)(out + (size_t)p * 128 + c4) = pk;
  }
}

// ---------------- classifier: bf16 MFMA GEMM (M=19 pad 32) + int bias; out NCHW f32 ----------------
__global__ __launch_bounds__(256) void cls_kernel(const unsigned char* __restrict__ in,
                                                  float* __restrict__ out,
                                                  const unsigned short* __restrict__ r5,
                                                  const float2* __restrict__ cst5) {
  __shared__ unsigned char lds[16384];
  int tid = threadIdx.x;
  int p0 = blockIdx.x << 6;
  #pragma unroll
  for (int it = 0; it < 2; it++) {
    int idx = tid + (it << 8);
    int p = idx >> 3, q = idx & 7;
    int kc = q >> 1, lg = (q & 1) << 1, pt = p >> 4;
    u32x4 g = *(const u32x4*)(in + (size_t)(p0 + p) * 128 + q * 16);
    unsigned int a0, a1, a2, a3, a4, a5, a6, a7;
    cvt2(g.x, a0, a1); cvt2(g.y, a2, a3); cvt2(g.z, a4, a5); cvt2(g.w, a6, a7);
    int l1 = (p & 15) | (lg << 4);
    int ad = (((((pt << 2) + kc) << 6) | l1) << 4);
    *(u32x4*)(lds + ad)       = u32x4{a0, a1, a2, a3};
    *(u32x4*)(lds + ad + 256) = u32x4{a4, a5, a6, a7};
  }
  __syncthreads();
  int l = tid & 63, pt = tid >> 6;
  bf16x8 af[2][4];
  #pragma unroll
  for (int ot = 0; ot < 2; ot++)
    #pragma unroll
    for (int kc = 0; kc < 4; kc++) {
      int o = (ot << 4) + (l & 15);
      int k = (kc << 5) + ((l >> 4) << 3);
      af[ot][kc] = *(const bf16x8*)(r5 + o * 128 + k);
    }
  f32x4 acc[2] = {{0,0,0,0},{0,0,0,0}};
  #pragma unroll
  for (int kc = 0; kc < 4; kc++) {
    bf16x8 b = *(const bf16x8*)(lds + (((((pt << 2) + kc) << 6) + l) << 4));
    acc[0] = __builtin_amdgcn_mfma_f32_16x16x32_bf16(af[0][kc], b, acc[0], 0, 0, 0);
    acc[1] = __builtin_amdgcn_mfma_f32_16x16x32_bf16(af[1][kc], b, acc[1], 0, 0, 0);
  }
  int p = p0 + (pt << 4) + (l & 15);
  int bb = p >> 15, hw = p & 32767;
  float* ob = out + (((size_t)bb * 19) << 15) + hw;
  #pragma unroll
  for (int ot = 0; ot < 2; ot++) {
    int obase = (ot << 4) + ((l >> 4) << 2);
    f32x4 a = acc[ot];
    #pragma unroll
    for (int i = 0; i < 4; i++) {
      int o = obase + i;
      if (o < 19) {
        float2 c5 = cst5[o];
        ob[(size_t)o << 15] = fmaf(a[i], c5.x, c5.y);
      }
    }
  }
}

// ---------------- launch ----------------
extern "C" void kernel_launch(void* const* d_in, const int* in_sizes, int n_in,
                              void* d_out, int out_size, void* d_ws, size_t ws_size,
                              hipStream_t stream) {
  (void)in_sizes; (void)n_in; (void)out_size; (void)ws_size;
  char* ws = (char*)d_ws;
  PArgs P;
  P.dw1  = (const float*)d_in[1];
  P.pw1  = (const float*)d_in[2];
  P.dw2  = (const float*)d_in[3];
  P.pw2  = (const float*)d_in[4];
  P.clsw = (const float*)d_in[5];
  P.clsb = (const float*)d_in[6];
  P.g1 = (const float*)d_in[7];  P.b1 = (const float*)d_in[8];
  P.m1 = (const float*)d_in[9];  P.v1 = (const float*)d_in[10];
  P.g2 = (const float*)d_in[11]; P.b2 = (const float*)d_in[12];
  P.m2 = (const float*)d_in[13]; P.v2 = (const float*)d_in[14];
  P.g3 = (const float*)d_in[15]; P.b3 = (const float*)d_in[16];
  P.m3 = (const float*)d_in[17]; P.v3 = (const float*)d_in[18];
  P.g4 = (const float*)d_in[19]; P.b4 = (const float*)d_in[20];
  P.m4 = (const float*)d_in[21]; P.v4 = (const float*)d_in[22];
  P.s1 = (const float*)d_in[23]; P.s2 = (const float*)d_in[24];
  P.s3 = (const float*)d_in[25]; P.s4 = (const float*)d_in[26];

  const float* x = (const float*)d_in[0];
  unsigned char* bufA = (unsigned char*)(ws + OFF_BUFA);
  unsigned char* bufB = (unsigned char*)(ws + OFF_BUFB);

  prep_kernel<<<544, 64, 0, stream>>>(P, ws);
  dw1_kernel<<<4096, 256, 0, stream>>>(x, ws, P.s1);                       // x -> k1 (A)
  pw_kernel<<<8192, 256, 0, stream>>>(bufA, bufB,
      (const unsigned short*)(ws + OFF_R2BF), (const f32x4*)(ws + OFF_CST2), P.s2);  // k1 -> k2 (B)
  dw2_kernel<<<8192, 256, 0, stream>>>(bufB, bufA, ws, P.s3);              // k2 -> k3 (A)
  pw_kernel<<<8192, 256, 0, stream>>>(bufA, bufB,
      (const unsigned short*)(ws + OFF_R4BF), (const f32x4*)(ws + OFF_CST4), P.s4);  // k3 -> k4 (B)
  cls_kernel<<<4096, 256, 0, stream>>>(bufB, (float*)d_out,
      (const unsigned short*)(ws + OFF_R5BF), (const float2*)(ws + OFF_CST5));       // k4 -> out
}

// Round 2
// 236.088 us; speedup vs baseline: 1.2898x; 1.2898x over previous
//
#include <hip/hip_runtime.h>

typedef __attribute__((ext_vector_type(4))) float f32x4;
typedef __attribute__((ext_vector_type(8))) short bf16x8;
typedef __attribute__((ext_vector_type(4))) unsigned int u32x4;

#define EPSV 1e-5f

// workspace layout (bytes)
#define OFF_BUFA 0u
#define OFF_BUFB 33554432u
#define OFF_T    67108864u
#define OFF_WQ1  (OFF_T + 0u)       // f32 [128][12]  (9 taps used)
#define OFF_R3F  (OFF_T + 6144u)    // f32 [9][128]   integer-valued
#define OFF_CST3 (OFF_T + 10752u)   // f32x4 [128]
#define OFF_CST1 (OFF_T + 12800u)   // f32x4 [128]
#define OFF_R2BF (OFF_T + 14848u)   // bf16 [128][128]
#define OFF_CST2 (OFF_T + 47616u)   // f32x4 [128]
#define OFF_R4BF (OFF_T + 49664u)   // bf16 [128][128]
#define OFF_CST4 (OFF_T + 82432u)   // f32x4 [128]
#define OFF_R5BF (OFF_T + 84480u)   // bf16 [32][128] (rows 19..31 zero)
#define OFF_CST5 (OFF_T + 92672u)   // float2 [32]

struct PArgs {
  const float *dw1, *pw1, *dw2, *pw2, *clsw, *clsb;
  const float *g1, *b1, *m1, *v1;
  const float *g2, *b2, *m2, *v2;
  const float *g3, *b3, *m3, *v3;
  const float *g4, *b4, *m4, *v4;
  const float *s1, *s2, *s3, *s4;
};

__device__ __forceinline__ unsigned short f2bf(float f) {
  return (unsigned short)(__builtin_bit_cast(unsigned int, f) >> 16);
}
__device__ __forceinline__ float clip7(float r) { return fminf(fmaxf(r, -7.f), 7.f); }

// y = a*A; t = (y-m)*sc + b; k = clamp(rint(t/s),0,15).  c = {A, sc, m, b}
__device__ __forceinline__ unsigned int qstep(float a, f32x4 c, float s) {
  float t = (a * c.x - c.z) * c.y + c.w;
  float u = t / s;
  float k = fminf(fmaxf(rintf(u), 0.f), 15.f);
  return (unsigned int)k;
}

// 4 u8 -> 2 dwords of packed bf16
__device__ __forceinline__ void cvt2(unsigned int d, unsigned int &lo, unsigned int &hi) {
  float f0 = (float)(d & 0xffu);
  float f1 = (float)((d >> 8) & 0xffu);
  float f2 = (float)((d >> 16) & 0xffu);
  float f3 = (float)(d >> 24);
  lo = (__builtin_bit_cast(unsigned int, f0) >> 16) | (__builtin_bit_cast(unsigned int, f1) & 0xffff0000u);
  hi = (__builtin_bit_cast(unsigned int, f2) >> 16) | (__builtin_bit_cast(unsigned int, f3) & 0xffff0000u);
}

__device__ __forceinline__ float wmax16(float v) {
  #pragma unroll
  for (int s = 1; s < 16; s <<= 1) v = fmaxf(v, __shfl_xor(v, s));
  return v;
}
__device__ __forceinline__ float wmax64(float v) {
  #pragma unroll
  for (int s = 1; s < 64; s <<= 1) v = fmaxf(v, __shfl_xor(v, s));
  return v;
}

// ---------------- prep: quantize weights, fold BN constants ----------------
__global__ __launch_bounds__(64) void prep_kernel(PArgs P, char* __restrict__ ws) {
  int bi = blockIdx.x, l = threadIdx.x;
  float* wq1 = (float*)(ws + OFF_WQ1);
  float* r3f = (float*)(ws + OFF_R3F);
  f32x4* cst1 = (f32x4*)(ws + OFF_CST1);
  f32x4* cst2 = (f32x4*)(ws + OFF_CST2);
  f32x4* cst3 = (f32x4*)(ws + OFF_CST3);
  f32x4* cst4 = (f32x4*)(ws + OFF_CST4);
  unsigned short* r2 = (unsigned short*)(ws + OFF_R2BF);
  unsigned short* r4 = (unsigned short*)(ws + OFF_R4BF);
  unsigned short* r5 = (unsigned short*)(ws + OFF_R5BF);
  float2* cst5 = (float2*)(ws + OFF_CST5);

  if (bi < 128) {
    int c = bi;
    float w = (l < 9) ? P.dw1[c * 9 + l] : 0.f;
    float mx = wmax16(fabsf(w));
    float sq = fmaxf(mx / 7.0f, 1e-8f);
    if (l < 9) wq1[c * 12 + l] = clip7(rintf(w / sq)) * sq;
    if (l == 0) {
      float sc = P.g1[c] / sqrtf(P.v1[c] + EPSV);
      cst1[c] = f32x4{1.f, sc, P.m1[c], P.b1[c]};
    }
  } else if (bi < 256) {
    int o = bi - 128;
    float w0 = P.pw1[o * 128 + l], w1 = P.pw1[o * 128 + 64 + l];
    float mx = wmax64(fmaxf(fabsf(w0), fabsf(w1)));
    float sq = fmaxf(mx / 7.0f, 1e-8f);
    r2[o * 128 + l]      = f2bf(clip7(rintf(w0 / sq)));
    r2[o * 128 + 64 + l] = f2bf(clip7(rintf(w1 / sq)));
    if (l == 0) {
      float sc = P.g2[o] / sqrtf(P.v2[o] + EPSV);
      cst2[o] = f32x4{P.s1[0] * sq, sc, P.m2[o], P.b2[o]};
    }
  } else if (bi < 384) {
    int c = bi - 256;
    float w = (l < 9) ? P.dw2[c * 9 + l] : 0.f;
    float mx = wmax16(fabsf(w));
    float sq = fmaxf(mx / 7.0f, 1e-8f);
    if (l < 9) r3f[l * 128 + c] = clip7(rintf(w / sq));
    if (l == 0) {
      float sc = P.g3[c] / sqrtf(P.v3[c] + EPSV);
      cst3[c] = f32x4{P.s2[0] * sq, sc, P.m3[c], P.b3[c]};
    }
  } else if (bi < 512) {
    int o = bi - 384;
    float w0 = P.pw2[o * 128 + l], w1 = P.pw2[o * 128 + 64 + l];
    float mx = wmax64(fmaxf(fabsf(w0), fabsf(w1)));
    float sq = fmaxf(mx / 7.0f, 1e-8f);
    r4[o * 128 + l]      = f2bf(clip7(rintf(w0 / sq)));
    r4[o * 128 + 64 + l] = f2bf(clip7(rintf(w1 / sq)));
    if (l == 0) {
      float sc = P.g4[o] / sqrtf(P.v4[o] + EPSV);
      cst4[o] = f32x4{P.s3[0] * sq, sc, P.m4[o], P.b4[o]};
    }
  } else {
    int o = bi - 512;
    if (o < 19) {
      float w0 = P.clsw[o * 128 + l], w1 = P.clsw[o * 128 + 64 + l];
      float mx = wmax64(fmaxf(fabsf(w0), fabsf(w1)));
      float sq = fmaxf(mx / 7.0f, 1e-8f);
      r5[o * 128 + l]      = f2bf(clip7(rintf(w0 / sq)));
      r5[o * 128 + 64 + l] = f2bf(clip7(rintf(w1 / sq)));
      if (l == 0) {
        float A5 = P.s4[0] * sq;
        float bq = rintf(P.clsb[o] / A5) * A5;
        cst5[o] = make_float2(A5, bq);
      }
    } else {
      r5[o * 128 + l] = 0; r5[o * 128 + 64 + l] = 0;
      if (l == 0) cst5[o] = make_float2(0.f, 0.f);
    }
  }
}

// ---------------- dw-conv1 v2: vectorized, (b,h)-row blocks, XCD-chunked ----------------
// thread = (wq = tid&63 -> w=4*wq.., cg = tid>>6), loop 32 channels.
// 3 aligned f32x4 loads per channel; neighbors via shfl; identical fmaf order to r1.
// LDS tile: byte (w, c) at  w*128 + (c ^ ((wq&31)<<2))  -> conflict-free u32 writes.
__global__ __launch_bounds__(256) void dw1_kernel(const float* __restrict__ x,
                                                  char* __restrict__ ws,
                                                  const float* __restrict__ s1p) {
  __shared__ __align__(16) unsigned char tile[32768];
  int bid = blockIdx.x;
  int orig = ((bid & 7) << 7) + (bid >> 3);   // XCD-chunked: XCD x -> b=x, h sequential
  int b = orig >> 7, h = orig & 127;
  int tid = threadIdx.x;
  int wq = tid & 63, cg = tid >> 6;
  const float* wq1 = (const float*)(ws + OFF_WQ1);
  const f32x4* cst1 = (const f32x4*)(ws + OFF_CST1);
  float s_act = *s1p;
  int w0 = wq << 2;
  int sw = (wq & 31) << 2;

  unsigned int acc0 = 0, acc1 = 0, acc2 = 0, acc3 = 0;
  #pragma unroll 4
  for (int cc = 0; cc < 32; cc++) {
    int c = (cg << 5) + cc;
    const float* wp = wq1 + c * 12;
    float k0 = wp[0], k1 = wp[1], k2 = wp[2], k3 = wp[3], k4 = wp[4],
          k5 = wp[5], k6 = wp[6], k7 = wp[7], k8 = wp[8];
    const float* xp = x + (((size_t)((b << 7) | c)) << 15) + (h << 8) + w0;
    f32x4 vm = {0.f, 0.f, 0.f, 0.f}, vp = {0.f, 0.f, 0.f, 0.f};
    f32x4 v0 = *(const f32x4*)(xp);
    if (h > 0)   vm = *(const f32x4*)(xp - 256);
    if (h < 127) vp = *(const f32x4*)(xp + 256);
    float lm = __shfl_up(vm.w, 1), l0 = __shfl_up(v0.w, 1), lp = __shfl_up(vp.w, 1);
    float rm = __shfl_down(vm.x, 1), r0 = __shfl_down(v0.x, 1), rp = __shfl_down(vp.x, 1);
    if (wq == 0)  { lm = 0.f; l0 = 0.f; lp = 0.f; }
    if (wq == 63) { rm = 0.f; r0 = 0.f; rp = 0.f; }

    float y0 = 0.f, y1 = 0.f, y2 = 0.f, y3 = 0.f;
    // row -1 (k0,k1,k2) then row 0 (k3,k4,k5) then row +1 (k6,k7,k8) — r1 order
    y0 = fmaf(lm,   k0, y0); y0 = fmaf(vm.x, k1, y0); y0 = fmaf(vm.y, k2, y0);
    y1 = fmaf(vm.x, k0, y1); y1 = fmaf(vm.y, k1, y1); y1 = fmaf(vm.z, k2, y1);
    y2 = fmaf(vm.y, k0, y2); y2 = fmaf(vm.z, k1, y2); y2 = fmaf(vm.w, k2, y2);
    y3 = fmaf(vm.z, k0, y3); y3 = fmaf(vm.w, k1, y3); y3 = fmaf(rm,   k2, y3);

    y0 = fmaf(l0,   k3, y0); y0 = fmaf(v0.x, k4, y0); y0 = fmaf(v0.y, k5, y0);
    y1 = fmaf(v0.x, k3, y1); y1 = fmaf(v0.y, k4, y1); y1 = fmaf(v0.z, k5, y1);
    y2 = fmaf(v0.y, k3, y2); y2 = fmaf(v0.z, k4, y2); y2 = fmaf(v0.w, k5, y2);
    y3 = fmaf(v0.z, k3, y3); y3 = fmaf(v0.w, k4, y3); y3 = fmaf(r0,   k5, y3);

    y0 = fmaf(lp,   k6, y0); y0 = fmaf(vp.x, k7, y0); y0 = fmaf(vp.y, k8, y0);
    y1 = fmaf(vp.x, k6, y1); y1 = fmaf(vp.y, k7, y1); y1 = fmaf(vp.z, k8, y1);
    y2 = fmaf(vp.y, k6, y2); y2 = fmaf(vp.z, k7, y2); y2 = fmaf(vp.w, k8, y2);
    y3 = fmaf(vp.z, k6, y3); y3 = fmaf(vp.w, k7, y3); y3 = fmaf(rp,   k8, y3);

    f32x4 cs = cst1[c];
    int sh = (cc & 3) << 3;
    acc0 |= qstep(y0, cs, s_act) << sh;
    acc1 |= qstep(y1, cs, s_act) << sh;
    acc2 |= qstep(y2, cs, s_act) << sh;
    acc3 |= qstep(y3, cs, s_act) << sh;
    if ((cc & 3) == 3) {
      int c0 = c - 3;
      *(unsigned int*)(tile + ((w0 + 0) << 7) + (c0 ^ sw)) = acc0;
      *(unsigned int*)(tile + ((w0 + 1) << 7) + (c0 ^ sw)) = acc1;
      *(unsigned int*)(tile + ((w0 + 2) << 7) + (c0 ^ sw)) = acc2;
      *(unsigned int*)(tile + ((w0 + 3) << 7) + (c0 ^ sw)) = acc3;
      acc0 = acc1 = acc2 = acc3 = 0;
    }
  }
  __syncthreads();
  // cooperative store: logical 16B chunk g=(p,s); physical chunk s^px, words ^s23
  unsigned char* gout = (unsigned char*)(ws + OFF_BUFA) + ((size_t)orig << 15);
  #pragma unroll
  for (int it = 0; it < 8; it++) {
    int idx = (it << 8) + tid;
    int p = idx >> 3, s = idx & 7;
    int px = (p >> 4) & 7, s23 = (p >> 2) & 3;
    u32x4 ch = *(const u32x4*)(tile + (p << 7) + ((s ^ px) << 4));
    unsigned int t0 = ch.x, t1 = ch.y, t2 = ch.z, t3 = ch.w, tt;
    if (s23 & 1) { tt = t0; t0 = t1; t1 = tt; tt = t2; t2 = t3; t3 = tt; }
    if (s23 & 2) { tt = t0; t0 = t2; t2 = tt; tt = t1; t1 = t3; t3 = tt; }
    *(u32x4*)(gout + (idx << 4)) = u32x4{t0, t1, t2, t3};
  }
}

// ---------------- pointwise conv (bf16 MFMA, exact int) + BN + qrelu ----------------
__global__ __launch_bounds__(256) void pw_kernel(const unsigned char* __restrict__ in,
                                                 unsigned char* __restrict__ out,
                                                 const unsigned short* __restrict__ rbf,
                                                 const f32x4* __restrict__ cst,
                                                 const float* __restrict__ sp) {
  __shared__ unsigned char lds[8192];
  int tid = threadIdx.x;
  int p0 = blockIdx.x << 5;
  {
    int p = tid >> 3, q = tid & 7;
    int kc = q >> 1, lg = (q & 1) << 1, pt = p >> 4;
    u32x4 g = *(const u32x4*)(in + (size_t)(p0 + p) * 128 + q * 16);
    unsigned int a0, a1, a2, a3, a4, a5, a6, a7;
    cvt2(g.x, a0, a1); cvt2(g.y, a2, a3); cvt2(g.z, a4, a5); cvt2(g.w, a6, a7);
    int l1 = (p & 15) | (lg << 4);
    int ad = (((((pt << 2) + kc) << 6) | l1) << 4);
    *(u32x4*)(lds + ad)       = u32x4{a0, a1, a2, a3};
    *(u32x4*)(lds + ad + 256) = u32x4{a4, a5, a6, a7};
  }
  __syncthreads();
  int l = tid & 63, wv = tid >> 6;
  int ob = wv << 5;
  bf16x8 af[2][4];
  #pragma unroll
  for (int ot = 0; ot < 2; ot++)
    #pragma unroll
    for (int kc = 0; kc < 4; kc++) {
      int o = ob + (ot << 4) + (l & 15);
      int k = (kc << 5) + ((l >> 4) << 3);
      af[ot][kc] = *(const bf16x8*)(rbf + o * 128 + k);
    }
  f32x4 acc[2][2] = {{{0,0,0,0},{0,0,0,0}},{{0,0,0,0},{0,0,0,0}}};
  #pragma unroll
  for (int kc = 0; kc < 4; kc++) {
    bf16x8 b0 = *(const bf16x8*)(lds + (((kc << 6) + l) << 4));
    bf16x8 b1 = *(const bf16x8*)(lds + ((((4 + kc) << 6) + l) << 4));
    #pragma unroll
    for (int ot = 0; ot < 2; ot++) {
      acc[ot][0] = __builtin_amdgcn_mfma_f32_16x16x32_bf16(af[ot][kc], b0, acc[ot][0], 0, 0, 0);
      acc[ot][1] = __builtin_amdgcn_mfma_f32_16x16x32_bf16(af[ot][kc], b1, acc[ot][1], 0, 0, 0);
    }
  }
  float s_act = *sp;
  #pragma unroll
  for (int ot = 0; ot < 2; ot++) {
    int o0 = ob + (ot << 4) + ((l >> 4) << 2);
    f32x4 c0 = cst[o0], c1 = cst[o0 + 1], c2 = cst[o0 + 2], c3 = cst[o0 + 3];
    #pragma unroll
    for (int pt = 0; pt < 2; pt++) {
      int p = p0 + (pt << 4) + (l & 15);
      f32x4 a = acc[ot][pt];
      unsigned int pk = qstep(a.x, c0, s_act) | (qstep(a.y, c1, s_act) << 8) |
                        (qstep(a.z, c2, s_act) << 16) | (qstep(a.w, c3, s_act) << 24);
      *(unsigned int*)(out + (size_t)p * 128 + o0) = pk;
    }
  }
}

// ---------------- dw-conv2 (exact int in fp32) + BN3 + qrelu ----------------
__global__ __launch_bounds__(256) void dw2_kernel(const unsigned char* __restrict__ in,
                                                  unsigned char* __restrict__ out,
                                                  const char* __restrict__ ws,
                                                  const float* __restrict__ sp) {
  __shared__ float tabs[1664];
  const float* src = (const float*)(ws + OFF_R3F);
  for (int i = threadIdx.x; i < 1664; i += 256) tabs[i] = src[i];
  __syncthreads();
  int tid = threadIdx.x;
  int cq = tid & 31, pl = tid >> 5;
  int c4 = cq << 2;
  float wk[9][4];
  #pragma unroll
  for (int t = 0; t < 9; t++) {
    wk[t][0] = tabs[t * 128 + c4];     wk[t][1] = tabs[t * 128 + c4 + 1];
    wk[t][2] = tabs[t * 128 + c4 + 2]; wk[t][3] = tabs[t * 128 + c4 + 3];
  }
  const f32x4* cst3 = (const f32x4*)(tabs + 1152);
  f32x4 cs0 = cst3[c4], cs1 = cst3[c4 + 1], cs2 = cst3[c4 + 2], cs3 = cst3[c4 + 3];
  float s_act = *sp;
  int p0 = blockIdx.x << 5;
  #pragma unroll
  for (int j = 0; j < 4; j++) {
    int p = p0 + pl + (j << 3);
    int w = p & 255, hh = (p >> 8) & 127;
    float a0 = 0.f, a1 = 0.f, a2 = 0.f, a3 = 0.f;
    #pragma unroll
    for (int dh = -1; dh <= 1; dh++) {
      if (hh + dh < 0 || hh + dh > 127) continue;
      #pragma unroll
      for (int dw = -1; dw <= 1; dw++) {
        if (w + dw < 0 || w + dw > 255) continue;
        unsigned int v = *(const unsigned int*)(in + (size_t)(p + dh * 256 + dw) * 128 + c4);
        int t = (dh + 1) * 3 + (dw + 1);
        a0 = fmaf((float)(v & 0xffu),         wk[t][0], a0);
        a1 = fmaf((float)((v >> 8) & 0xffu),  wk[t][1], a1);
        a2 = fmaf((float)((v >> 16) & 0xffu), wk[t][2], a2);
        a3 = fmaf((float)(v >> 24),           wk[t][3], a3);
      }
    }
    unsigned int pk = qstep(a0, cs0, s_act) | (qstep(a1, cs1, s_act) << 8) |
                      (qstep(a2, cs2, s_act) << 16) | (qstep(a3, cs3, s_act) << 24);
    *(unsigned int*)(out + (size_t)p * 128 + c4) = pk;
  }
}

// ---------------- classifier ----------------
__global__ __launch_bounds__(256) void cls_kernel(const unsigned char* __restrict__ in,
                                                  float* __restrict__ out,
                                                  const unsigned short* __restrict__ r5,
                                                  const float2* __restrict__ cst5) {
  __shared__ unsigned char lds[16384];
  int tid = threadIdx.x;
  int p0 = blockIdx.x << 6;
  #pragma unroll
  for (int it = 0; it < 2; it++) {
    int idx = tid + (it << 8);
    int p = idx >> 3, q = idx & 7;
    int kc = q >> 1, lg = (q & 1) << 1, pt = p >> 4;
    u32x4 g = *(const u32x4*)(in + (size_t)(p0 + p) * 128 + q * 16);
    unsigned int a0, a1, a2, a3, a4, a5, a6, a7;
    cvt2(g.x, a0, a1); cvt2(g.y, a2, a3); cvt2(g.z, a4, a5); cvt2(g.w, a6, a7);
    int l1 = (p & 15) | (lg << 4);
    int ad = (((((pt << 2) + kc) << 6) | l1) << 4);
    *(u32x4*)(lds + ad)       = u32x4{a0, a1, a2, a3};
    *(u32x4*)(lds + ad + 256) = u32x4{a4, a5, a6, a7};
  }
  __syncthreads();
  int l = tid & 63, pt = tid >> 6;
  bf16x8 af[2][4];
  #pragma unroll
  for (int ot = 0; ot < 2; ot++)
    #pragma unroll
    for (int kc = 0; kc < 4; kc++) {
      int o = (ot << 4) + (l & 15);
      int k = (kc << 5) + ((l >> 4) << 3);
      af[ot][kc] = *(const bf16x8*)(r5 + o * 128 + k);
    }
  f32x4 acc[2] = {{0,0,0,0},{0,0,0,0}};
  #pragma unroll
  for (int kc = 0; kc < 4; kc++) {
    bf16x8 b = *(const bf16x8*)(lds + (((((pt << 2) + kc) << 6) + l) << 4));
    acc[0] = __builtin_amdgcn_mfma_f32_16x16x32_bf16(af[0][kc], b, acc[0], 0, 0, 0);
    acc[1] = __builtin_amdgcn_mfma_f32_16x16x32_bf16(af[1][kc], b, acc[1], 0, 0, 0);
  }
  int p = p0 + (pt << 4) + (l & 15);
  int bb = p >> 15, hw = p & 32767;
  float* ob = out + (((size_t)bb * 19) << 15) + hw;
  #pragma unroll
  for (int ot = 0; ot < 2; ot++) {
    int obase = (ot << 4) + ((l >> 4) << 2);
    f32x4 a = acc[ot];
    #pragma unroll
    for (int i = 0; i < 4; i++) {
      int o = obase + i;
      if (o < 19) {
        float2 c5 = cst5[o];
        ob[(size_t)o << 15] = fmaf(a[i], c5.x, c5.y);
      }
    }
  }
}

// ---------------- launch ----------------
extern "C" void kernel_launch(void* const* d_in, const int* in_sizes, int n_in,
                              void* d_out, int out_size, void* d_ws, size_t ws_size,
                              hipStream_t stream) {
  (void)in_sizes; (void)n_in; (void)out_size; (void)ws_size;
  char* ws = (char*)d_ws;
  PArgs P;
  P.dw1  = (const float*)d_in[1];
  P.pw1  = (const float*)d_in[2];
  P.dw2  = (const float*)d_in[3];
  P.pw2  = (const float*)d_in[4];
  P.clsw = (const float*)d_in[5];
  P.clsb = (const float*)d_in[6];
  P.g1 = (const float*)d_in[7];  P.b1 = (const float*)d_in[8];
  P.m1 = (const float*)d_in[9];  P.v1 = (const float*)d_in[10];
  P.g2 = (const float*)d_in[11]; P.b2 = (const float*)d_in[12];
  P.m2 = (const float*)d_in[13]; P.v2 = (const float*)d_in[14];
  P.g3 = (const float*)d_in[15]; P.b3 = (const float*)d_in[16];
  P.m3 = (const float*)d_in[17]; P.v3 = (const float*)d_in[18];
  P.g4 = (const float*)d_in[19]; P.b4 = (const float*)d_in[20];
  P.m4 = (const float*)d_in[21]; P.v4 = (const float*)d_in[22];
  P.s1 = (const float*)d_in[23]; P.s2 = (const float*)d_in[24];
  P.s3 = (const float*)d_in[25]; P.s4 = (const float*)d_in[26];

  const float* x = (const float*)d_in[0];
  unsigned char* bufA = (unsigned char*)(ws + OFF_BUFA);
  unsigned char* bufB = (unsigned char*)(ws + OFF_BUFB);

  prep_kernel<<<544, 64, 0, stream>>>(P, ws);
  dw1_kernel<<<1024, 256, 0, stream>>>(x, ws, P.s1);                       // x -> k1 (A)
  pw_kernel<<<8192, 256, 0, stream>>>(bufA, bufB,
      (const unsigned short*)(ws + OFF_R2BF), (const f32x4*)(ws + OFF_CST2), P.s2);  // k1 -> k2 (B)
  dw2_kernel<<<8192, 256, 0, stream>>>(bufB, bufA, ws, P.s3);              // k2 -> k3 (A)
  pw_kernel<<<8192, 256, 0, stream>>>(bufA, bufB,
      (const unsigned short*)(ws + OFF_R4BF), (const f32x4*)(ws + OFF_CST4), P.s4);  // k3 -> k4 (B)
  cls_kernel<<<4096, 256, 0, stream>>>(bufB, (float*)d_out,
      (const unsigned short*)(ws + OFF_R5BF), (const float2*)(ws + OFF_CST5));       // k4 -> out
}